// Round 10
// baseline (30.636 us; speedup 1.0000x reference)
//
#include <hip/hip_runtime.h>

#define T_LEN  512
#define K_LEN  64
#define NFILT  32
#define NBATCH 64
#define XOFS   64                 // pad: min element index = XOFS-63 = 1
#define XS_SZ  672                // max read idx = (XOFS-0) + 607 = 671
#define SQRT_LOG2E 1.2011224087864498f
#define LN2        0.6931471805599453f

// result[lane] = src[lane-1], lane0 -> 0 (DPP wave_shr:1, bound_ctrl=1)
static __device__ __forceinline__ float wave_shr1(float x) {
    int r = __builtin_amdgcn_update_dpp(0, __builtin_bit_cast(int, x),
                                        0x138, 0xF, 0xF, true);
    return __builtin_bit_cast(float, r);
}

template <int N>
static __device__ __forceinline__ float row_ror(float x) {
    int r = __builtin_amdgcn_update_dpp(0, __builtin_bit_cast(int, x),
                                        0x120 + N, 0xF, 0xF, true);
    return __builtin_bit_cast(float, r);
}

static __device__ __forceinline__ float exp2_fast(float x) {
#if __has_builtin(__builtin_amdgcn_exp2f)
    return __builtin_amdgcn_exp2f(x);
#else
    return exp2f(x);
#endif
}

// Linear-domain band-limited soft-DTW, 2 problems/wave (f, f+16; same b),
// 1024 waves. Z = 2^S2 * exp(-D);
// Z[i,j] = exp(-C[i,j]) * (Z[i-1,j] + Z[i,j-1] + Z[i-1,j-1]).
//
// FUSED SOFTWARE PIPELINE (in-order-issue aware): each step of chunk c's
// serial core is interleaved, in program order, with one step of chunk c+1's
// w-precompute (2 fma + sel + 2 exp, chain-independent) and one ds_read for
// chunk c+2. sched_barrier(0) after every step pins the interleave so the
// scheduler cannot re-cluster into phases (R9 proved phases = null: an
// in-order wave cannot fill core-chain stalls with already-executed batch
// work). exp latency resolves one chunk later; ds_read 32 steps later.
__global__ __launch_bounds__(256, 1) void dtw_kernel(const float* __restrict__ x,
                                                     const float* __restrict__ protos,
                                                     float* __restrict__ out) {
    __shared__ float xs[XS_SZ];
    const int tid  = threadIdx.x;
    const int lane = tid & 63;
    const int wid  = tid >> 6;
    const int b    = blockIdx.x >> 2;               // 256 blocks: 4 per b
    const int fA   = ((blockIdx.x & 3) << 2) | wid; // 0..15
    const int fB   = fA + 16;

    for (int t0i = tid; t0i < XS_SZ; t0i += 256) {
        int i = t0i - XOFS;
        xs[t0i] = (i >= 0 && i < T_LEN) ? x[b * T_LEN + i] * SQRT_LOG2E : 0.0f;
    }
    __syncthreads();

    const float pAn = -protos[fA * K_LEN + lane] * SQRT_LOG2E;
    const float pBn = -protos[fB * K_LEN + lane] * SQRT_LOG2E;
    const float jj  = (float)lane / 63.0f;

    // exact fp32 band interval per column (same predicate as reference)
    int a0 = 0, b0 = T_LEN - 1;
    while (a0 < b0) { int m = (a0 + b0) >> 1;
        if ((float)m / 511.0f - jj >= -0.2f) b0 = m; else a0 = m + 1; }
    const int ilo = a0;
    a0 = 0; b0 = T_LEN - 1;
    while (a0 < b0) { int m = (a0 + b0 + 1) >> 1;
        if ((float)m / 511.0f - jj <= 0.2f) a0 = m; else b0 = m - 1; }
    const int ihi = a0;

    const unsigned range = (unsigned)(ihi - ilo);
    unsigned tb = (unsigned)(-(lane + ilo));        // w-precompute mask counter
    float prevA = 0.0f, prevB = 0.0f;
    float dgpA  = (lane == 0) ? 1.0f : 0.0f;        // Z[-1,-1] = 1
    float dgpB  = dgpA;
    int   S2A = 0, S2B = 0;
    const float* bp = &xs[XOFS - lane];

    float xvP[32], xvQ[32];                         // x for chunk c+1 (rotating)
    float wUA[32], wUB[32], wVA[32], wVB[32];       // w buffers (rotating)

    // ---- prologue: w for chunk 0 into wU; x of chunk 1 into xvP ----
    {
        float x0[32];
#pragma unroll
        for (int k = 0; k < 32; ++k) x0[k] = bp[k];
#pragma unroll
        for (int k = 0; k < 32; ++k) xvP[k] = bp[32 + k];
#pragma unroll
        for (int k = 0; k < 32; ++k) {
            float sel = (tb <= range) ? 0.0f : -3.0e38f; ++tb;
            float dA = x0[k] + pAn, dB = x0[k] + pBn;
            wUA[k] = exp2_fast(__builtin_fmaf(dA, -dA, sel));
            wUB[k] = exp2_fast(__builtin_fmaf(dB, -dB, sel));
        }
        bp += 64;                                   // bp -> chunk c+2 region
    }

    // wave-uniform power-of-2 renorm to max ~ 2^30 (Me = 284-e), cadence 32
#define RENORM_HALF(PV, DG, S2) do {                                         \
        float m_ = PV;                                                       \
        m_ = fmaxf(m_, row_ror<8>(m_));                                      \
        m_ = fmaxf(m_, row_ror<4>(m_));                                      \
        m_ = fmaxf(m_, row_ror<2>(m_));                                      \
        m_ = fmaxf(m_, row_ror<1>(m_));                                      \
        int mi_ = __builtin_bit_cast(int, m_);                               \
        unsigned r0_ = (unsigned)__builtin_amdgcn_readlane(mi_, 0);          \
        unsigned r1_ = (unsigned)__builtin_amdgcn_readlane(mi_, 16);         \
        unsigned r2_ = (unsigned)__builtin_amdgcn_readlane(mi_, 32);         \
        unsigned r3_ = (unsigned)__builtin_amdgcn_readlane(mi_, 48);         \
        unsigned ra_ = r0_ > r1_ ? r0_ : r1_;                                \
        unsigned rb_ = r2_ > r3_ ? r2_ : r3_;                                \
        unsigned mx_ = ra_ > rb_ ? ra_ : rb_;                                \
        int e_  = (int)((mx_ >> 23) & 0xFF);                                 \
        int Me_ = 284 - e_;                                                  \
        Me_ = Me_ < 1 ? 1 : (Me_ > 254 ? 254 : Me_);                         \
        float M_ = __builtin_bit_cast(float, Me_ << 23);                     \
        S2 += Me_ - 127;                                                     \
        PV *= M_;                                                            \
        DG *= M_;                                                            \
    } while (0)

#define RENORM() do { RENORM_HALF(prevA, dgpA, S2A);                         \
                      RENORM_HALF(prevB, dgpB, S2B); } while (0)

    // fused chunk: core(c) with WC*, w-precompute(c+1) from XVU into WN*,
    // ds_read(c+2) into XVF. One sched region per step.
#define FUSED(XVU, XVF, WCA, WCB, WNA, WNB) do {                             \
        _Pragma("unroll")                                                    \
        for (int k = 0; k < 32; ++k) {                                       \
            XVF[k] = bp[k + 0];  /* chunk c+2, consumed next chunk */        \
            float sel_ = (tb <= range) ? 0.0f : -3.0e38f; ++tb;              \
            float dA_ = XVU[k] + pAn;                                        \
            float dB_ = XVU[k] + pBn;                                        \
            WNA[k] = exp2_fast(__builtin_fmaf(dA_, -dA_, sel_));             \
            WNB[k] = exp2_fast(__builtin_fmaf(dB_, -dB_, sel_));             \
            asm volatile("" : "+v"(WNA[k]), "+v"(WNB[k]));                   \
            float lA_ = wave_shr1(prevA);                                    \
            float lB_ = wave_shr1(prevB);                                    \
            float aA_ = prevA + dgpA;                                        \
            float aB_ = prevB + dgpB;                                        \
            dgpA = lA_; dgpB = lB_;                                          \
            prevA = (aA_ + lA_) * WCA[k];                                    \
            prevB = (aB_ + lB_) * WCB[k];                                    \
            __builtin_amdgcn_sched_barrier(0);                               \
        }                                                                    \
        bp += 32;                                                            \
        RENORM();                                                            \
    } while (0)

    // 17 fused chunks (c = 0..16); parity rotates the buffers
#pragma unroll 1
    for (int cc = 0; cc < 8; ++cc) {
        FUSED(xvP, xvQ, wUA, wUB, wVA, wVB);   // c even
        FUSED(xvQ, xvP, wVA, wVB, wUA, wUB);   // c odd
    }
    FUSED(xvP, xvQ, wUA, wUB, wVA, wVB);       // c = 16 (fills chunk-17 w in wV)

    // final: chunk 17 core-only, 31 steps (g = 544..574)
#pragma unroll
    for (int k = 0; k < 31; ++k) {
        float lA_ = wave_shr1(prevA);
        float lB_ = wave_shr1(prevB);
        float aA_ = prevA + dgpA;
        float aB_ = prevB + dgpB;
        dgpA = lA_; dgpB = lB_;
        prevA = (aA_ + lA_) * wVA[k];
        prevB = (aB_ + lB_) * wVB[k];
    }

    if (lane == 63) {
        float DA = ((float)S2A - log2f(prevA)) * LN2;
        float DB = ((float)S2B - log2f(prevB)) * LN2;
        out[b * NFILT + fA] = DA * (1.0f / (float)T_LEN);
        out[b * NFILT + fB] = DB * (1.0f / (float)T_LEN);
    }
#undef FUSED
#undef RENORM_HALF
#undef RENORM
}

extern "C" void kernel_launch(void* const* d_in, const int* in_sizes, int n_in,
                              void* d_out, int out_size, void* d_ws, size_t ws_size,
                              hipStream_t stream) {
    const float* x      = (const float*)d_in[0];
    const float* protos = (const float*)d_in[1];
    float* out          = (float*)d_out;

    dim3 grid(NBATCH * 4);   // 256 blocks x 4 waves = 1024 waves (1/SIMD)
    dim3 block(256);         // each wave: 2 problems (f, f+16), same b
    hipLaunchKernelGGL(dtw_kernel, grid, block, 0, stream, x, protos, out);
}

// Round 12
// 27.485 us; speedup vs baseline: 1.1147x; 1.1147x over previous
//
#include <hip/hip_runtime.h>

#define T_LEN  512
#define K_LEN  64
#define NFILT  32
#define NBATCH 64
#define XOFS   64                // pad: min element index = XOFS-63 >= 1
#define XS_SZ  640               // max element index read = 639
#define CHUNK  32
#define SQRT_LOG2E 1.2011224087864498f
#define LN2        0.6931471805599453f

typedef __attribute__((ext_vector_type(2))) float f32x2;

// result[lane] = src[lane-1], lane0 -> 0 (DPP wave_shr:1, bound_ctrl=1)
static __device__ __forceinline__ float wave_shr1(float x) {
    int r = __builtin_amdgcn_update_dpp(0, __builtin_bit_cast(int, x),
                                        0x138, 0xF, 0xF, true);
    return __builtin_bit_cast(float, r);
}

static __device__ __forceinline__ f32x2 wave_shr1_x2(f32x2 v) {
    f32x2 r;
    r.x = wave_shr1(v.x);
    r.y = wave_shr1(v.y);
    return r;
}

template <int N>
static __device__ __forceinline__ float row_ror(float x) {
    int r = __builtin_amdgcn_update_dpp(0, __builtin_bit_cast(int, x),
                                        0x120 + N, 0xF, 0xF, true);
    return __builtin_bit_cast(float, r);
}

static __device__ __forceinline__ float exp2_fast(float x) {
#if __has_builtin(__builtin_amdgcn_exp2f)
    return __builtin_amdgcn_exp2f(x);
#else
    return exp2f(x);
#endif
}

// Linear-domain band-limited soft-DTW, 2 problems/wave (f, f+16; same b),
// 1024 waves. Z = 2^S2 * exp(-D);
// Z[i,j] = exp(-C[i,j]) * (Z[i-1,j] + Z[i,j-1] + Z[i-1,j-1]).
// R12: R11's packed-f32 state (v_pk_add/mul) with the scaling-convention
// bug fixed: xs is PRE-SCALED by sqrt(log2 e), so d = xv + pn (pn = -p*s).
// R11 wrongly applied fma(xv, s, pn) on the already-scaled xv.
__global__ __launch_bounds__(256) void dtw_kernel(const float* __restrict__ x,
                                                  const float* __restrict__ protos,
                                                  float* __restrict__ out) {
    __shared__ float xs[XS_SZ];
    const int tid  = threadIdx.x;
    const int lane = tid & 63;
    const int wid  = tid >> 6;
    const int b    = blockIdx.x >> 2;               // 256 blocks: 4 per b
    const int fA   = ((blockIdx.x & 3) << 2) | wid; // 0..15
    const int fB   = fA + 16;

    for (int t0 = tid; t0 < XS_SZ; t0 += 256) {
        int i = t0 - XOFS;
        xs[t0] = (i >= 0 && i < T_LEN) ? x[b * T_LEN + i] * SQRT_LOG2E : 0.0f;
    }
    __syncthreads();

    const float pAn = -protos[fA * K_LEN + lane] * SQRT_LOG2E;
    const float pBn = -protos[fB * K_LEN + lane] * SQRT_LOG2E;
    const float jj  = (float)lane / 63.0f;

    // exact fp32 band interval per column (same predicate as reference)
    int a0 = 0, b0 = T_LEN - 1;
    while (a0 < b0) { int m = (a0 + b0) >> 1;
        if ((float)m / 511.0f - jj >= -0.2f) b0 = m; else a0 = m + 1; }
    const int ilo = a0;
    a0 = 0; b0 = T_LEN - 1;
    while (a0 < b0) { int m = (a0 + b0 + 1) >> 1;
        if ((float)m / 511.0f - jj <= 0.2f) a0 = m; else b0 = m - 1; }
    const int ihi = a0;

    const unsigned range = (unsigned)(ihi - ilo);
    unsigned t = (unsigned)(-(lane + ilo));
    f32x2 prev2 = {0.0f, 0.0f};
    const float d0 = (lane == 0) ? 1.0f : 0.0f;     // Z[-1,-1] = 1
    f32x2 dgp2 = {d0, d0};
    int   S2A = 0, S2B = 0;
    int   base = XOFS - lane;

    float A[CHUNK], Bv[CHUNK];
#pragma unroll
    for (int k = 0; k < CHUNK; ++k) A[k] = xs[base + k];
    __builtin_amdgcn_sched_barrier(0);

    // band mask folded into exp arg: out-of-band -> exp2(-3e38) == 0 exactly
#define STEP(XV) do {                                         \
        float xv_  = (XV);                                    \
        float sel_ = (t <= range) ? 0.0f : -3.0e38f;          \
        ++t;                                                  \
        float dA_ = xv_ + pAn;   /* xv pre-scaled; pn=-p*s */ \
        float dB_ = xv_ + pBn;                                \
        f32x2 w2_;                                            \
        w2_.x = exp2_fast(__builtin_fmaf(dA_, -dA_, sel_));   \
        w2_.y = exp2_fast(__builtin_fmaf(dB_, -dB_, sel_));   \
        f32x2 l2_ = wave_shr1_x2(prev2);                      \
        f32x2 a2_ = prev2 + dgp2;      /* v_pk_add_f32 */     \
        f32x2 s2_ = a2_ + l2_;         /* v_pk_add_f32 */     \
        dgp2  = l2_;                                          \
        prev2 = s2_ * w2_;             /* v_pk_mul_f32 */     \
    } while (0)

    // wave-uniform power-of-2 renorm to max ~ 2^30 (Me = 284-e), cadence 32;
    // per-problem M computed scalar, applied packed.
#define RENORM() do {                                                        \
        float MA_, MB_;                                                      \
        {                                                                    \
            float m_ = prev2.x;                                              \
            m_ = fmaxf(m_, row_ror<8>(m_));                                  \
            m_ = fmaxf(m_, row_ror<4>(m_));                                  \
            m_ = fmaxf(m_, row_ror<2>(m_));                                  \
            m_ = fmaxf(m_, row_ror<1>(m_));                                  \
            int mi_ = __builtin_bit_cast(int, m_);                           \
            unsigned r0_ = (unsigned)__builtin_amdgcn_readlane(mi_, 0);      \
            unsigned r1_ = (unsigned)__builtin_amdgcn_readlane(mi_, 16);     \
            unsigned r2_ = (unsigned)__builtin_amdgcn_readlane(mi_, 32);     \
            unsigned r3_ = (unsigned)__builtin_amdgcn_readlane(mi_, 48);     \
            unsigned ra_ = r0_ > r1_ ? r0_ : r1_;                            \
            unsigned rb_ = r2_ > r3_ ? r2_ : r3_;                            \
            unsigned mx_ = ra_ > rb_ ? ra_ : rb_;                            \
            int e_  = (int)((mx_ >> 23) & 0xFF);                             \
            int Me_ = 284 - e_;                                              \
            Me_ = Me_ < 1 ? 1 : (Me_ > 254 ? 254 : Me_);                     \
            MA_ = __builtin_bit_cast(float, Me_ << 23);                      \
            S2A += Me_ - 127;                                                \
        }                                                                    \
        {                                                                    \
            float m_ = prev2.y;                                              \
            m_ = fmaxf(m_, row_ror<8>(m_));                                  \
            m_ = fmaxf(m_, row_ror<4>(m_));                                  \
            m_ = fmaxf(m_, row_ror<2>(m_));                                  \
            m_ = fmaxf(m_, row_ror<1>(m_));                                  \
            int mi_ = __builtin_bit_cast(int, m_);                           \
            unsigned r0_ = (unsigned)__builtin_amdgcn_readlane(mi_, 0);      \
            unsigned r1_ = (unsigned)__builtin_amdgcn_readlane(mi_, 16);     \
            unsigned r2_ = (unsigned)__builtin_amdgcn_readlane(mi_, 32);     \
            unsigned r3_ = (unsigned)__builtin_amdgcn_readlane(mi_, 48);     \
            unsigned ra_ = r0_ > r1_ ? r0_ : r1_;                            \
            unsigned rb_ = r2_ > r3_ ? r2_ : r3_;                            \
            unsigned mx_ = ra_ > rb_ ? ra_ : rb_;                            \
            int e_  = (int)((mx_ >> 23) & 0xFF);                             \
            int Me_ = 284 - e_;                                              \
            Me_ = Me_ < 1 ? 1 : (Me_ > 254 ? 254 : Me_);                     \
            MB_ = __builtin_bit_cast(float, Me_ << 23);                      \
            S2B += Me_ - 127;                                                \
        }                                                                    \
        f32x2 M2_ = {MA_, MB_};                                              \
        prev2 = prev2 * M2_;           /* v_pk_mul_f32 */                    \
        dgp2  = dgp2  * M2_;           /* v_pk_mul_f32 */                    \
    } while (0)

#pragma unroll 1
    for (int cc = 0; cc < 8; ++cc) {
        // prefetch next chunk into Bv, pinned BEFORE this chunk's compute
#pragma unroll
        for (int k = 0; k < CHUNK; ++k) Bv[k] = xs[base + CHUNK + k];
        __builtin_amdgcn_sched_barrier(0);
#pragma unroll
        for (int k = 0; k < CHUNK; ++k) STEP(A[k]);
        RENORM();
        __builtin_amdgcn_sched_barrier(0);
        base += CHUNK;
        // prefetch next chunk into A, pinned BEFORE this chunk's compute
#pragma unroll
        for (int k = 0; k < CHUNK; ++k) A[k] = xs[base + CHUNK + k];
        __builtin_amdgcn_sched_barrier(0);
#pragma unroll
        for (int k = 0; k < CHUNK; ++k) STEP(Bv[k]);
        RENORM();
        __builtin_amdgcn_sched_barrier(0);
        base += CHUNK;
    }
    // steps 512..543 with A; prefetch tail (544..574 + pad) into Bv
#pragma unroll
    for (int k = 0; k < CHUNK; ++k) Bv[k] = xs[base + CHUNK + k];
    __builtin_amdgcn_sched_barrier(0);
#pragma unroll
    for (int k = 0; k < CHUNK; ++k) STEP(A[k]);
    RENORM();
    // tail: steps 544..574 (31 steps)
#pragma unroll
    for (int k = 0; k < 31; ++k) STEP(Bv[k]);

    if (lane == 63) {
        float DA = ((float)S2A - log2f(prev2.x)) * LN2;
        float DB = ((float)S2B - log2f(prev2.y)) * LN2;
        out[b * NFILT + fA] = DA * (1.0f / (float)T_LEN);
        out[b * NFILT + fB] = DB * (1.0f / (float)T_LEN);
    }
#undef STEP
#undef RENORM
}

extern "C" void kernel_launch(void* const* d_in, const int* in_sizes, int n_in,
                              void* d_out, int out_size, void* d_ws, size_t ws_size,
                              hipStream_t stream) {
    const float* x      = (const float*)d_in[0];
    const float* protos = (const float*)d_in[1];
    float* out          = (float*)d_out;

    dim3 grid(NBATCH * 4);   // 256 blocks; 4 waves/block = 1 wave/SIMD
    dim3 block(256);         // each wave: 2 problems (f, f+16), same b
    hipLaunchKernelGGL(dtw_kernel, grid, block, 0, stream, x, protos, out);
}

// Round 13
// 27.420 us; speedup vs baseline: 1.1173x; 1.0024x over previous
//
#include <hip/hip_runtime.h>

#define T_LEN  512
#define K_LEN  64
#define NFILT  32
#define NBATCH 64
#define XOFS   64                // pad: min element index = XOFS-63 >= 1
#define XS_SZ  640               // max element index read = 639
#define CHUNK  32
#define SQRT_LOG2E 1.2011224087864498f
#define LN2        0.6931471805599453f

typedef __attribute__((ext_vector_type(2))) float f32x2;

// result[lane] = src[lane-1], lane0 -> 0 (DPP wave_shr:1, bound_ctrl=1)
static __device__ __forceinline__ float wave_shr1(float x) {
    int r = __builtin_amdgcn_update_dpp(0, __builtin_bit_cast(int, x),
                                        0x138, 0xF, 0xF, true);
    return __builtin_bit_cast(float, r);
}

static __device__ __forceinline__ f32x2 wave_shr1_x2(f32x2 v) {
    f32x2 r;
    r.x = wave_shr1(v.x);
    r.y = wave_shr1(v.y);
    return r;
}

template <int N>
static __device__ __forceinline__ float row_ror(float x) {
    int r = __builtin_amdgcn_update_dpp(0, __builtin_bit_cast(int, x),
                                        0x120 + N, 0xF, 0xF, true);
    return __builtin_bit_cast(float, r);
}

static __device__ __forceinline__ float exp2_fast(float x) {
#if __has_builtin(__builtin_amdgcn_exp2f)
    return __builtin_amdgcn_exp2f(x);
#else
    return exp2f(x);
#endif
}

// Linear-domain band-limited soft-DTW, 2 problems/wave (f, f+16; same b),
// 1024 waves. Z = 2^S2 * exp(-D);
// Z[i,j] = exp(-C[i,j]) * (Z[i-1,j] + Z[i,j-1] + Z[i-1,j-1]).
//
// R13: DPP HOISTED OFF THE CHAIN. Loop-carried L2 = S(prev2): the shr1 of
// P[d] issues the instant P[d] exists and is consumed only at step d+1,
// with the NEXT step's w-computation (sel + adds + fmas + 2 exp2) placed
// between issue and use as gap filler. w is likewise computed one step
// ahead (exp latency off-chain). Dataflow identical to R12 per step:
//   up = prev2, left = L2(in), diag = dgp2;  dgp2' = L2(in); L2' = S(P).
__global__ __launch_bounds__(256) void dtw_kernel(const float* __restrict__ x,
                                                  const float* __restrict__ protos,
                                                  float* __restrict__ out) {
    __shared__ float xs[XS_SZ];
    const int tid  = threadIdx.x;
    const int lane = tid & 63;
    const int wid  = tid >> 6;
    const int b    = blockIdx.x >> 2;               // 256 blocks: 4 per b
    const int fA   = ((blockIdx.x & 3) << 2) | wid; // 0..15
    const int fB   = fA + 16;

    for (int t0 = tid; t0 < XS_SZ; t0 += 256) {
        int i = t0 - XOFS;
        xs[t0] = (i >= 0 && i < T_LEN) ? x[b * T_LEN + i] * SQRT_LOG2E : 0.0f;
    }
    __syncthreads();

    const float pAn = -protos[fA * K_LEN + lane] * SQRT_LOG2E;
    const float pBn = -protos[fB * K_LEN + lane] * SQRT_LOG2E;
    const float jj  = (float)lane / 63.0f;

    // exact fp32 band interval per column (same predicate as reference)
    int a0 = 0, b0 = T_LEN - 1;
    while (a0 < b0) { int m = (a0 + b0) >> 1;
        if ((float)m / 511.0f - jj >= -0.2f) b0 = m; else a0 = m + 1; }
    const int ilo = a0;
    a0 = 0; b0 = T_LEN - 1;
    while (a0 < b0) { int m = (a0 + b0 + 1) >> 1;
        if ((float)m / 511.0f - jj <= 0.2f) a0 = m; else b0 = m - 1; }
    const int ihi = a0;

    const unsigned range = (unsigned)(ihi - ilo);
    unsigned t = (unsigned)(-(lane + ilo));
    f32x2 prev2 = {0.0f, 0.0f};
    f32x2 L2    = {0.0f, 0.0f};                     // S(P[-1]) = 0
    const float d0 = (lane == 0) ? 1.0f : 0.0f;     // Z[-1,-1] = 1
    f32x2 dgp2 = {d0, d0};
    f32x2 w2;                                       // w for the CURRENT step
    int   S2A = 0, S2B = 0;
    int   base = XOFS - lane;

    float A[CHUNK], Bv[CHUNK];
#pragma unroll
    for (int k = 0; k < CHUNK; ++k) A[k] = xs[base + k];
    __builtin_amdgcn_sched_barrier(0);

    // prologue: w for step 0
    {
        float xv_  = A[0];
        float sel_ = (t <= range) ? 0.0f : -3.0e38f;
        ++t;
        float dA_ = xv_ + pAn;
        float dB_ = xv_ + pBn;
        w2.x = exp2_fast(__builtin_fmaf(dA_, -dA_, sel_));
        w2.y = exp2_fast(__builtin_fmaf(dB_, -dB_, sel_));
    }

    // STEP for diagonal g: consume (w2 = w[g], L2 = S(P[g-1]), dgp2 = S(P[g-2]));
    // issue L2' = S(P[g]) immediately; then compute w[g+1] from XVN (gap filler).
#define STEP(XVN) do {                                        \
        f32x2 a2_ = prev2 + dgp2;      /* up + diag  */       \
        f32x2 s2_ = a2_ + L2;          /* + left     */       \
        f32x2 P_  = s2_ * w2;                                 \
        dgp2  = L2;                                           \
        prev2 = P_;                                           \
        L2 = wave_shr1_x2(P_);         /* issue early */      \
        float xv_  = (XVN);                                   \
        float sel_ = (t <= range) ? 0.0f : -3.0e38f;          \
        ++t;                                                  \
        float dA_ = xv_ + pAn;                                \
        float dB_ = xv_ + pBn;                                \
        w2.x = exp2_fast(__builtin_fmaf(dA_, -dA_, sel_));    \
        w2.y = exp2_fast(__builtin_fmaf(dB_, -dB_, sel_));    \
    } while (0)

    // wave-uniform power-of-2 renorm to max ~ 2^30 (Me = 284-e), cadence 32;
    // rescales ALL scaled state: prev2, dgp2, L2.
#define RENORM() do {                                                        \
        float MA_, MB_;                                                      \
        {                                                                    \
            float m_ = prev2.x;                                              \
            m_ = fmaxf(m_, row_ror<8>(m_));                                  \
            m_ = fmaxf(m_, row_ror<4>(m_));                                  \
            m_ = fmaxf(m_, row_ror<2>(m_));                                  \
            m_ = fmaxf(m_, row_ror<1>(m_));                                  \
            int mi_ = __builtin_bit_cast(int, m_);                           \
            unsigned r0_ = (unsigned)__builtin_amdgcn_readlane(mi_, 0);      \
            unsigned r1_ = (unsigned)__builtin_amdgcn_readlane(mi_, 16);     \
            unsigned r2_ = (unsigned)__builtin_amdgcn_readlane(mi_, 32);     \
            unsigned r3_ = (unsigned)__builtin_amdgcn_readlane(mi_, 48);     \
            unsigned ra_ = r0_ > r1_ ? r0_ : r1_;                            \
            unsigned rb_ = r2_ > r3_ ? r2_ : r3_;                            \
            unsigned mx_ = ra_ > rb_ ? ra_ : rb_;                            \
            int e_  = (int)((mx_ >> 23) & 0xFF);                             \
            int Me_ = 284 - e_;                                              \
            Me_ = Me_ < 1 ? 1 : (Me_ > 254 ? 254 : Me_);                     \
            MA_ = __builtin_bit_cast(float, Me_ << 23);                      \
            S2A += Me_ - 127;                                                \
        }                                                                    \
        {                                                                    \
            float m_ = prev2.y;                                              \
            m_ = fmaxf(m_, row_ror<8>(m_));                                  \
            m_ = fmaxf(m_, row_ror<4>(m_));                                  \
            m_ = fmaxf(m_, row_ror<2>(m_));                                  \
            m_ = fmaxf(m_, row_ror<1>(m_));                                  \
            int mi_ = __builtin_bit_cast(int, m_);                           \
            unsigned r0_ = (unsigned)__builtin_amdgcn_readlane(mi_, 0);      \
            unsigned r1_ = (unsigned)__builtin_amdgcn_readlane(mi_, 16);     \
            unsigned r2_ = (unsigned)__builtin_amdgcn_readlane(mi_, 32);     \
            unsigned r3_ = (unsigned)__builtin_amdgcn_readlane(mi_, 48);     \
            unsigned ra_ = r0_ > r1_ ? r0_ : r1_;                            \
            unsigned rb_ = r2_ > r3_ ? r2_ : r3_;                            \
            unsigned mx_ = ra_ > rb_ ? ra_ : rb_;                            \
            int e_  = (int)((mx_ >> 23) & 0xFF);                             \
            int Me_ = 284 - e_;                                              \
            Me_ = Me_ < 1 ? 1 : (Me_ > 254 ? 254 : Me_);                     \
            MB_ = __builtin_bit_cast(float, Me_ << 23);                      \
            S2B += Me_ - 127;                                                \
        }                                                                    \
        f32x2 M2_ = {MA_, MB_};                                              \
        prev2 = prev2 * M2_;                                                 \
        dgp2  = dgp2  * M2_;                                                 \
        L2    = L2    * M2_;                                                 \
    } while (0)

    // run 32 diagonals consuming CUR; last step's w-feed comes from NEXT0
#define RUN32(CUR, NEXT0) do {                                               \
        _Pragma("unroll")                                                    \
        for (int k = 0; k < 31; ++k) STEP(CUR[k + 1]);                       \
        STEP(NEXT0);                                                         \
    } while (0)

#pragma unroll 1
    for (int cc = 0; cc < 8; ++cc) {
#pragma unroll
        for (int k = 0; k < CHUNK; ++k) Bv[k] = xs[base + CHUNK + k];
        __builtin_amdgcn_sched_barrier(0);
        RUN32(A, Bv[0]);                 // steps 64cc .. 64cc+31
        RENORM();
        __builtin_amdgcn_sched_barrier(0);
        base += CHUNK;
#pragma unroll
        for (int k = 0; k < CHUNK; ++k) A[k] = xs[base + CHUNK + k];
        __builtin_amdgcn_sched_barrier(0);
        RUN32(Bv, A[0]);                 // steps 64cc+32 .. 64cc+63
        RENORM();
        __builtin_amdgcn_sched_barrier(0);
        base += CHUNK;
    }
    // steps 512..543 with A; prefetch tail x (544..575 incl pad) into Bv
#pragma unroll
    for (int k = 0; k < CHUNK; ++k) Bv[k] = xs[base + CHUNK + k];
    __builtin_amdgcn_sched_barrier(0);
    RUN32(A, Bv[0]);
    RENORM();
    // tail: steps 544..574 (31 steps); final STEP feeds a dummy (discarded w)
#pragma unroll
    for (int k = 0; k < 30; ++k) STEP(Bv[k + 1]);
    STEP(Bv[31]);

    if (lane == 63) {
        float DA = ((float)S2A - log2f(prev2.x)) * LN2;
        float DB = ((float)S2B - log2f(prev2.y)) * LN2;
        out[b * NFILT + fA] = DA * (1.0f / (float)T_LEN);
        out[b * NFILT + fB] = DB * (1.0f / (float)T_LEN);
    }
#undef STEP
#undef RENORM
#undef RUN32
}

extern "C" void kernel_launch(void* const* d_in, const int* in_sizes, int n_in,
                              void* d_out, int out_size, void* d_ws, size_t ws_size,
                              hipStream_t stream) {
    const float* x      = (const float*)d_in[0];
    const float* protos = (const float*)d_in[1];
    float* out          = (float*)d_out;

    dim3 grid(NBATCH * 4);   // 256 blocks; 4 waves/block = 1 wave/SIMD
    dim3 block(256);         // each wave: 2 problems (f, f+16), same b
    hipLaunchKernelGGL(dtw_kernel, grid, block, 0, stream, x, protos, out);
}